// Round 13
// baseline (52.725 us; speedup 1.0000x reference)
//
#include <hip/hip_runtime.h>
#include <hip/hip_bf16.h>

#define BATCH   262144
#define FIN     128
#define FINP    129            // fan_in + 1 (bias col)
#define FOUT    128
#define NT64    (BATCH / 64)   // 4096 block-iterations of 64 rows

#define BIAS_OFF   32768       // 128x128 bf16 Wmat (row-major), then 128 f32 bias
#define WS_BYTES   33280

typedef __attribute__((ext_vector_type(8)))  short  short8;            // 8 bf16
typedef __attribute__((ext_vector_type(4)))  unsigned short ushort4e;  // 4 bf16 (8 B)
typedef __attribute__((ext_vector_type(4)))  float  f32x4;
typedef __attribute__((ext_vector_type(16))) float  f32x16;            // 32x32 MFMA C/D

// f32 -> bf16 RNE via scalar cast: compiler emits v_cvt_pk_bf16_f32 for pairs
// (m240: hand-rolled bit-twiddle is ~5x more VALU on the staging critical path).
__device__ inline unsigned short f2bf(float f) {
    __hip_bfloat16 h = __float2bfloat16(f);
    return *reinterpret_cast<unsigned short*>(&h);
}

// --- Kernel 1: gather W[hash_idx] once into d_ws (row-major bf16 Wmat + f32 bias) ---
__global__ __launch_bounds__(256)
void gather_w(const float* __restrict__ W, const int* __restrict__ hidx,
              unsigned char* __restrict__ ws) {
    int t = blockIdx.x * 256 + threadIdx.x;
    if (t < FOUT * FIN) {
        int n = t >> 7;
        int k = t & 127;
        *(unsigned short*)(ws + n * 256 + k * 2) = f2bf(W[hidx[n * FINP + k]]);
    } else if (t < FOUT * FIN + FOUT) {
        int n = t - FOUT * FIN;
        *(float*)(ws + BIAS_OFF + n * 4) = W[hidx[n * FINP + FIN]];  // bias, fp32 exact
    }
}

// --- Kernel 2: W-in-registers GEMM, LDS-staged A; lgkmcnt-only barrier; prefetch
//     issued BEFORE the barrier (not drained, since the barrier skips vmcnt). ---
__global__ __launch_bounds__(512, 4)
void hashed_mfma(const float* __restrict__ a, const unsigned char* __restrict__ ws,
                 float* __restrict__ out) {
    // Two 64x128 bf16 A-tiles, rows 256 B, swizzled: byte ^= (row&15)<<4.
    __shared__ __align__(16) unsigned char lds[2][64 * 256];

    const int tid  = threadIdx.x;
    const int wave = tid >> 6;
    const int lane = tid & 63;
    const int rt_l = wave >> 2;    // which 32-row half of the 64-row stage
    const int cb   = wave & 3;     // col-block (32 out cols)
    const int r    = lane & 31;    // batch row within tile (A) / W row (B)
    const int hk   = lane >> 5;    // k-half (8 consecutive k)
    const int n    = cb * 32 + r;  // Wmat row = out col for this lane

    // W row held entirely in registers: wf[kk] = Wmat[n][kk*16 + hk*8 .. +7].
    short8 wf[8];
    #pragma unroll
    for (int kk = 0; kk < 8; ++kk)
        wf[kk] = *reinterpret_cast<const short8*>(ws + n * 256 + kk * 32 + hk * 16);
    const float bias = *reinterpret_cast<const float*>(ws + BIAS_OFF + n * 4);

    // Staging map: load i (i=0..3) is global float idx i*2048 + tid*4 of the 64-row
    // chunk -> row = i*16 + (tid>>5), colbyte = (tid&31)*8 in bf16 LDS.
    unsigned int loff[4];
    #pragma unroll
    for (int i = 0; i < 4; ++i) {
        unsigned int row = i * 16 + (tid >> 5);
        loff[i] = (row * 256 + (tid & 31) * 8) ^ ((row & 15) << 4);
    }

    const unsigned int abase = (unsigned)((rt_l * 32 + r) * 256);
    const unsigned int aswz  = ((unsigned)(r & 15)) << 4;

    const f32x4* A4 = reinterpret_cast<const f32x4*>(a);
    const int stride = gridDim.x;
    int it = blockIdx.x;

    // Prologue: first chunk's loads (coalesced: 512 lanes x 16 B contiguous).
    f32x4 ar[4];
    #pragma unroll
    for (int i = 0; i < 4; ++i)
        ar[i] = A4[(size_t)it * 2048 + i * 512 + tid];

    int p = 0;
    while (it < NT64) {
        // Convert (v_cvt_pk_bf16_f32 pairs) and stage into lds[p].
        #pragma unroll
        for (int i = 0; i < 4; ++i) {
            ushort4e b;
            b[0] = f2bf(ar[i][0]); b[1] = f2bf(ar[i][1]);
            b[2] = f2bf(ar[i][2]); b[3] = f2bf(ar[i][3]);
            *reinterpret_cast<ushort4e*>(&lds[p][loff[i]]) = b;
        }

        // Prefetch the NEXT chunk BEFORE the barrier — the lgkm-only barrier does
        // not drain vmcnt, so these loads stay in flight across it and gain the
        // barrier-skew time for free.  (ar regs were fully consumed above.)
        const int nxt = it + stride;
        if (nxt < NT64) {
            #pragma unroll
            for (int i = 0; i < 4; ++i)
                ar[i] = A4[(size_t)nxt * 2048 + i * 512 + tid];
        }

        // lgkmcnt-only barrier: LDS writes must be visible block-wide, but global
        // stores/loads are NOT drained.
        __builtin_amdgcn_sched_barrier(0);
        asm volatile("s_waitcnt lgkmcnt(0)" ::: "memory");
        __builtin_amdgcn_s_barrier();
        __builtin_amdgcn_sched_barrier(0);

        // Compute from lds[p]: 8 x (ds_read_b128 A-frag + 32x32x16 MFMA).
        f32x16 acc;
        #pragma unroll
        for (int e = 0; e < 16; ++e) acc[e] = bias;

        const unsigned char* buf = lds[p];
        #pragma unroll
        for (int kk = 0; kk < 8; ++kk) {
            short8 af = *reinterpret_cast<const short8*>(
                buf + ((abase + kk * 32 + hk * 16) ^ aswz));
            acc = __builtin_amdgcn_mfma_f32_32x32x16_bf16(af, wf[kk], acc, 0, 0, 0);
        }

        // C layout: col = lane&31 (out col n), row = (reg&3)+8*(reg>>2)+4*hk.
        // 16 dword stores; 32 lanes x 4B cover full aligned 128 B lines in L2.
        float* obase = out + (size_t)(it * 64 + rt_l * 32 + hk * 4) * FOUT + n;
        #pragma unroll
        for (int g = 0; g < 4; ++g) {
            #pragma unroll
            for (int q = 0; q < 4; ++q)
                obase[(size_t)(g * 8 + q) * FOUT] = acc[g * 4 + q];
        }

        it = nxt;
        p ^= 1;
    }
}

extern "C" void kernel_launch(void* const* d_in, const int* in_sizes, int n_in,
                              void* d_out, int out_size, void* d_ws, size_t ws_size,
                              hipStream_t stream) {
    const float* a    = (const float*)d_in[0];
    const float* W    = (const float*)d_in[1];
    const int*   hidx = (const int*)d_in[2];
    float*       out  = (float*)d_out;
    unsigned char* ws = (unsigned char*)d_ws;

    hipLaunchKernelGGL(gather_w, dim3((FOUT * FINP + 255) / 256), dim3(256), 0, stream,
                       W, hidx, ws);
    // 1024 blocks x 512 thr; 32 KB LDS -> 4 blocks/CU resident; 4 iterations/block.
    hipLaunchKernelGGL(hashed_mfma, dim3(1024), dim3(512), 0, stream,
                       a, ws, out);
}

// Round 14
// 49.897 us; speedup vs baseline: 1.0567x; 1.0567x over previous
//
#include <hip/hip_runtime.h>
#include <hip/hip_bf16.h>

#define BATCH   262144
#define FIN     128
#define FINP    129            // fan_in + 1 (bias col)
#define FOUT    128
#define NT64    (BATCH / 64)   // 4096 block-iterations of 64 rows

#define BIAS_OFF   32768       // 128x128 bf16 Wmat (row-major), then 128 f32 bias
#define WS_BYTES   33280

typedef __attribute__((ext_vector_type(8)))  short  short8;            // 8 bf16
typedef __attribute__((ext_vector_type(4)))  unsigned short ushort4e;  // 4 bf16 (8 B)
typedef __attribute__((ext_vector_type(4)))  float  f32x4;
typedef __attribute__((ext_vector_type(16))) float  f32x16;            // 32x32 MFMA C/D

// f32 -> bf16 RNE via scalar cast (compiler emits v_cvt_pk_bf16_f32 for pairs).
__device__ inline unsigned short f2bf(float f) {
    __hip_bfloat16 h = __float2bfloat16(f);
    return *reinterpret_cast<unsigned short*>(&h);
}

// --- Kernel 1: gather W[hash_idx] once into d_ws (row-major bf16 Wmat + f32 bias) ---
__global__ __launch_bounds__(256)
void gather_w(const float* __restrict__ W, const int* __restrict__ hidx,
              unsigned char* __restrict__ ws) {
    int t = blockIdx.x * 256 + threadIdx.x;
    if (t < FOUT * FIN) {
        int n = t >> 7;
        int k = t & 127;
        *(unsigned short*)(ws + n * 256 + k * 2) = f2bf(W[hidx[n * FINP + k]]);
    } else if (t < FOUT * FIN + FOUT) {
        int n = t - FOUT * FIN;
        *(float*)(ws + BIAS_OFF + n * 4) = W[hidx[n * FINP + FIN]];  // bias, fp32 exact
    }
}

// --- Kernel 2: W-in-registers GEMM, LDS-staged A; lgkmcnt-only barrier;
//     NONTEMPORAL full-line C-stores: out does not allocate in L2/L3, so `a`
//     stays L3-resident across replays (FETCH -> ~0). ---
__global__ __launch_bounds__(512, 4)
void hashed_mfma(const float* __restrict__ a, const unsigned char* __restrict__ ws,
                 float* __restrict__ out) {
    // Two 64x128 bf16 A-tiles, rows 256 B, swizzled: byte ^= (row&15)<<4.
    __shared__ __align__(16) unsigned char lds[2][64 * 256];

    const int tid  = threadIdx.x;
    const int wave = tid >> 6;
    const int lane = tid & 63;
    const int rt_l = wave >> 2;    // which 32-row half of the 64-row stage
    const int cb   = wave & 3;     // col-block (32 out cols)
    const int r    = lane & 31;    // batch row within tile (A) / W row (B)
    const int hk   = lane >> 5;    // k-half (8 consecutive k)
    const int n    = cb * 32 + r;  // Wmat row = out col for this lane

    // W row held entirely in registers: wf[kk] = Wmat[n][kk*16 + hk*8 .. +7].
    short8 wf[8];
    #pragma unroll
    for (int kk = 0; kk < 8; ++kk)
        wf[kk] = *reinterpret_cast<const short8*>(ws + n * 256 + kk * 32 + hk * 16);
    const float bias = *reinterpret_cast<const float*>(ws + BIAS_OFF + n * 4);

    // Staging map: load i (i=0..3) is global float idx i*2048 + tid*4 of the 64-row
    // chunk -> row = i*16 + (tid>>5), colbyte = (tid&31)*8 in bf16 LDS.
    unsigned int loff[4];
    #pragma unroll
    for (int i = 0; i < 4; ++i) {
        unsigned int row = i * 16 + (tid >> 5);
        loff[i] = (row * 256 + (tid & 31) * 8) ^ ((row & 15) << 4);
    }

    const unsigned int abase = (unsigned)((rt_l * 32 + r) * 256);
    const unsigned int aswz  = ((unsigned)(r & 15)) << 4;

    const f32x4* A4 = reinterpret_cast<const f32x4*>(a);
    const int stride = gridDim.x;
    int it = blockIdx.x;

    // Prologue: first chunk's loads (coalesced: 512 lanes x 16 B contiguous).
    f32x4 ar[4];
    #pragma unroll
    for (int i = 0; i < 4; ++i)
        ar[i] = A4[(size_t)it * 2048 + i * 512 + tid];

    int p = 0;
    while (it < NT64) {
        // Convert (v_cvt_pk_bf16_f32 pairs) and stage into lds[p].
        #pragma unroll
        for (int i = 0; i < 4; ++i) {
            ushort4e b;
            b[0] = f2bf(ar[i][0]); b[1] = f2bf(ar[i][1]);
            b[2] = f2bf(ar[i][2]); b[3] = f2bf(ar[i][3]);
            *reinterpret_cast<ushort4e*>(&lds[p][loff[i]]) = b;
        }

        // Prefetch the NEXT chunk BEFORE the barrier (barrier skips vmcnt drain).
        const int nxt = it + stride;
        if (nxt < NT64) {
            #pragma unroll
            for (int i = 0; i < 4; ++i)
                ar[i] = A4[(size_t)nxt * 2048 + i * 512 + tid];
        }

        // lgkmcnt-only barrier: LDS writes visible block-wide; global traffic
        // stays in flight.
        __builtin_amdgcn_sched_barrier(0);
        asm volatile("s_waitcnt lgkmcnt(0)" ::: "memory");
        __builtin_amdgcn_s_barrier();
        __builtin_amdgcn_sched_barrier(0);

        // Compute from lds[p]: 8 x (ds_read_b128 A-frag + 32x32x16 MFMA).
        f32x16 acc;
        #pragma unroll
        for (int e = 0; e < 16; ++e) acc[e] = bias;

        const unsigned char* buf = lds[p];
        #pragma unroll
        for (int kk = 0; kk < 8; ++kk) {
            short8 af = *reinterpret_cast<const short8*>(
                buf + ((abase + kk * 32 + hk * 16) ^ aswz));
            acc = __builtin_amdgcn_mfma_f32_32x32x16_bf16(af, wf[kk], acc, 0, 0, 0);
        }

        // C layout: col = lane&31 (out col n), row = (reg&3)+8*(reg>>2)+4*hk.
        // Each store instruction: 32 contiguous lanes x 4 B = full aligned 128 B
        // lines -> nontemporal is safe (no partial-line granule amplification)
        // and keeps out from evicting `a` out of L3.
        float* obase = out + (size_t)(it * 64 + rt_l * 32 + hk * 4) * FOUT + n;
        #pragma unroll
        for (int g = 0; g < 4; ++g) {
            #pragma unroll
            for (int q = 0; q < 4; ++q)
                __builtin_nontemporal_store(acc[g * 4 + q],
                                            obase + (size_t)(g * 8 + q) * FOUT);
        }

        it = nxt;
        p ^= 1;
    }
}

extern "C" void kernel_launch(void* const* d_in, const int* in_sizes, int n_in,
                              void* d_out, int out_size, void* d_ws, size_t ws_size,
                              hipStream_t stream) {
    const float* a    = (const float*)d_in[0];
    const float* W    = (const float*)d_in[1];
    const int*   hidx = (const int*)d_in[2];
    float*       out  = (float*)d_out;
    unsigned char* ws = (unsigned char*)d_ws;

    hipLaunchKernelGGL(gather_w, dim3((FOUT * FINP + 255) / 256), dim3(256), 0, stream,
                       W, hidx, ws);
    // 1024 blocks x 512 thr; 32 KB LDS -> 4 blocks/CU resident; 4 iterations/block.
    hipLaunchKernelGGL(hashed_mfma, dim3(1024), dim3(512), 0, stream,
                       a, ws, out);
}